// Round 1
// 351.532 us; speedup vs baseline: 1.0011x; 1.0011x over previous
//
#include <hip/hip_runtime.h>

#define C_IN 256
#define C_OUT 64
#define BSH 7                 // bucket = dst >> 7  (128 nodes/bucket)
#define NPB 128               // nodes per bucket
#define NB 1024               // max buckets (n <= 131072)
#define CHUNK 4096            // edges per binning block
#define ROWS 4                // table rows per thread in kA2 (256*4 >= nbin)

typedef short bf16x8 __attribute__((ext_vector_type(8)));
typedef float f32x4 __attribute__((ext_vector_type(4)));

__device__ __forceinline__ unsigned short f2bf(float f) {
    unsigned u = __builtin_bit_cast(unsigned, f);
    u = (u + 0x7FFFu + ((u >> 16) & 1u)) >> 16;
    return (unsigned short)u;
}
__device__ __forceinline__ float bflo(unsigned u) {
    return __builtin_bit_cast(float, u << 16);
}
__device__ __forceinline__ float bfhi(unsigned u) {
    return __builtin_bit_cast(float, u & 0xffff0000u);
}

// ---------------- one-shot: WT[n][k] = bf16(W[k][n]) ----------------
__global__ __launch_bounds__(256) void k_wt(const float* __restrict__ W,
                                            unsigned short* __restrict__ WT) {
#pragma unroll
    for (int i = 0; i < 16; ++i) {
        int f = i * 256 + threadIdx.x;   // float4 id over 256x64
        int k = f >> 4;
        int n4 = (f & 15) * 4;
        float4 v = ((const float4*)W)[f];
        WT[(n4 + 0) * 256 + k] = f2bf(v.x);
        WT[(n4 + 1) * 256 + k] = f2bf(v.y);
        WT[(n4 + 2) * 256 + k] = f2bf(v.z);
        WT[(n4 + 3) * 256 + k] = f2bf(v.w);
    }
}

// ---------------- per-(block,bucket) histogram table ----------------
__global__ __launch_bounds__(1024) void k_hist2(const int* __restrict__ dst,
                                                int* __restrict__ table, int e) {
    __shared__ int cnt[NB];
    if (threadIdx.x < NB) cnt[threadIdx.x] = 0;
    __syncthreads();
    int b0 = blockIdx.x * CHUNK;
#pragma unroll
    for (int k = 0; k < CHUNK / 1024; ++k) {
        int i = b0 + k * 1024 + threadIdx.x;
        if (i < e) atomicAdd(&cnt[dst[i] >> BSH], 1);
    }
    __syncthreads();
    if (threadIdx.x < NB) table[(size_t)blockIdx.x * NB + threadIdx.x] = cnt[threadIdx.x];
}

// ---------------- column-wise exclusive scan: one block per bucket ----------------
__global__ __launch_bounds__(256) void kA2(int* __restrict__ table,
                                           int* __restrict__ tot, int nbin) {
    __shared__ int part[256];
    int bucket = blockIdx.x;
    int t = threadIdx.x;
    int v[ROWS];
    int s = 0;
#pragma unroll
    for (int i = 0; i < ROWS; ++i) {
        int r = t * ROWS + i;
        int x = (r < nbin) ? table[(size_t)r * NB + bucket] : 0;
        v[i] = s;
        s += x;
    }
    part[t] = s;
    __syncthreads();
    for (int off = 1; off < 256; off <<= 1) {
        int u = (t >= off) ? part[t - off] : 0;
        __syncthreads();
        part[t] += u;
        __syncthreads();
    }
    int base = part[t] - s;  // exclusive over threads
#pragma unroll
    for (int i = 0; i < ROWS; ++i) {
        int r = t * ROWS + i;
        if (r < nbin) table[(size_t)r * NB + bucket] = v[i] + base;
    }
    if (t == 255) tot[bucket] = part[255];
}

// ---------------- bucket totals -> compact gbase ----------------
__global__ __launch_bounds__(1024) void kB(const int* __restrict__ tot,
                                           int* __restrict__ gbase, int e) {
    __shared__ int l[NB];
    int t = threadIdx.x;
    int v = tot[t];
    l[t] = v;
    __syncthreads();
    for (int off = 1; off < NB; off <<= 1) {
        int u = (t >= off) ? l[t - off] : 0;
        __syncthreads();
        l[t] += u;
        __syncthreads();
    }
    gbase[t] = l[t] - v;  // exclusive
    if (t == NB - 1) gbase[NB] = e;
}

// ---------------- single-pass atomic-free multisplit (1024 thr) ----------------
__global__ __launch_bounds__(1024) void k_bin2(const int* __restrict__ src,
                                               const int* __restrict__ dst,
                                               const int* __restrict__ table,
                                               const int* __restrict__ gbase,
                                               int* __restrict__ sorted, int e) {
    __shared__ int cur[NB];
    if (threadIdx.x < NB)
        cur[threadIdx.x] = table[(size_t)blockIdx.x * NB + threadIdx.x] + gbase[threadIdx.x];
    __syncthreads();
    int b0 = blockIdx.x * CHUNK;
#pragma unroll
    for (int k = 0; k < CHUNK / 1024; ++k) {
        int i = b0 + k * 1024 + threadIdx.x;
        if (i < e) {
            int d = dst[i];
            int bb = d >> BSH;
            int off = atomicAdd(&cur[bb], 1);
            sorted[off] = (src[i] << BSH) | (d & (NPB - 1));
        }
    }
}

// ---------------- in-bucket counting sort -> per-node CSR, plus dinv (512 thr) ----------------
__global__ __launch_bounds__(512) void k_sort2(const int* __restrict__ sorted,
                                               const int* __restrict__ gbase,
                                               int* __restrict__ eidx,
                                               int* __restrict__ rowptr,
                                               float* __restrict__ dinv, int n, int e) {
    __shared__ int cnt[NPB];
    __shared__ int sc[NPB];
    __shared__ int cur[NPB];
    int b = blockIdx.x;
    int node0 = b * NPB;
    int range = min(NPB, n - node0);
    int inbase = gbase[b];
    int m_b = gbase[b + 1] - inbase;
    if (threadIdx.x < NPB) cnt[threadIdx.x] = 0;
    __syncthreads();
    for (int j = threadIdx.x; j < m_b; j += 512)
        atomicAdd(&cnt[sorted[inbase + j] & (NPB - 1)], 1);
    __syncthreads();
    if (threadIdx.x < NPB) sc[threadIdx.x] = cnt[threadIdx.x];
    __syncthreads();
    for (int off = 1; off < NPB; off <<= 1) {
        int t = (threadIdx.x < NPB && threadIdx.x >= off) ? sc[threadIdx.x - off] : 0;
        __syncthreads();
        if (threadIdx.x < NPB) sc[threadIdx.x] += t;
        __syncthreads();
    }
    if (threadIdx.x < NPB) {
        int excl = inbase + sc[threadIdx.x] - cnt[threadIdx.x];
        cur[threadIdx.x] = excl;
        if (threadIdx.x < range) {
            rowptr[node0 + threadIdx.x] = excl;
            dinv[node0 + threadIdx.x] = rsqrtf((float)(cnt[threadIdx.x] + 1));
        }
    }
    __syncthreads();
    for (int j = threadIdx.x; j < m_b; j += 512) {
        int v = sorted[inbase + j];
        int pos = atomicAdd(&cur[v & (NPB - 1)], 1);
        eidx[pos] = v >> BSH;
    }
    if (b == 0 && threadIdx.x == 0) rowptr[n] = e;
}

// ---------------- h' = (x @ W) * dinv[row], bf16 MFMA, LDS-free ----------------
// A fragments loaded directly from x (fp32 -> bf16 in regs): for fixed m, lanes
// q=0..3 cover 128 contiguous bytes per row -> fully-used HBM segments.
// B fragments loaded directly from WT (32 KB, L2-resident): for fixed m, lanes
// q=0..3 cover 64 contiguous bytes -> full cachelines, pure L2 hits.
// No LDS, no barriers: occupancy limited only by VGPRs.
__global__ __launch_bounds__(256) void k_gemm(const float* __restrict__ x,
                                              const unsigned short* __restrict__ WT,
                                              const float* __restrict__ dinv,
                                              unsigned short* __restrict__ h, int n) {
    const int t = threadIdx.x;
    const int lane = t & 63;
    const int w = t >> 6;       // wave 0..3 -> rows 16w..16w+15
    const int m = lane & 15;
    const int q = lane >> 4;

    int arow = blockIdx.x * 64 + 16 * w + m;
    // clamp: garbage A rows only affect D rows >= n, which are never stored
    const float* xr = x + (size_t)(arow < n ? arow : 0) * C_IN + q * 8;

    // load + convert A fragments (8 ks x 8 floats = one full x row per lane)
    bf16x8 A[8];
#pragma unroll
    for (int ks = 0; ks < 8; ++ks) {
        float4 v0 = *(const float4*)&xr[ks * 32];
        float4 v1 = *(const float4*)&xr[ks * 32 + 4];
        bf16x8 a;
        a[0] = (short)f2bf(v0.x); a[1] = (short)f2bf(v0.y);
        a[2] = (short)f2bf(v0.z); a[3] = (short)f2bf(v0.w);
        a[4] = (short)f2bf(v1.x); a[5] = (short)f2bf(v1.y);
        a[6] = (short)f2bf(v1.z); a[7] = (short)f2bf(v1.w);
        A[ks] = a;
    }

    f32x4 acc[4];
#pragma unroll
    for (int nt = 0; nt < 4; ++nt) acc[nt] = (f32x4){0.f, 0.f, 0.f, 0.f};

    const unsigned short* wb = WT + (size_t)m * 256 + q * 8;
#pragma unroll
    for (int ks = 0; ks < 8; ++ks) {
#pragma unroll
        for (int nt = 0; nt < 4; ++nt) {
            bf16x8 B = *(const bf16x8*)&wb[nt * 16 * 256 + ks * 32];
            acc[nt] = __builtin_amdgcn_mfma_f32_16x16x32_bf16(A[ks], B, acc[nt], 0, 0, 0);
        }
    }

#pragma unroll
    for (int r = 0; r < 4; ++r) {
        int gr = blockIdx.x * 64 + 16 * w + q * 4 + r;
        if (gr < n) {
            float di = dinv[gr];
#pragma unroll
            for (int nt = 0; nt < 4; ++nt)
                h[(size_t)gr * C_OUT + nt * 16 + m] = f2bf(acc[nt][r] * di);
        }
    }
}

// ---------------- gather: 1 wave/node, 8 lanes/edge, uint4 (8 ch) per lane ----------------
// out[d] = dinv[d] * (sum_{s in N(d)} h'[s] + h'[d]) + b
__global__ __launch_bounds__(256) void k_gather(const int* __restrict__ rowptr,
                                                const int* __restrict__ eidx,
                                                const unsigned short* __restrict__ h,
                                                const float* __restrict__ dinv,
                                                const float* __restrict__ bias,
                                                float* __restrict__ out, int n) {
    int node = blockIdx.x * 4 + (threadIdx.x >> 6);
    if (node >= n) return;
    int lane = threadIdx.x & 63;
    int g = lane >> 3;          // edge slot 0..7
    int c8 = (lane & 7) * 8;    // channel base 0..56

    int beg = rowptr[node];
    int end = rowptr[node + 1];
    float a0 = 0.f, a1 = 0.f, a2 = 0.f, a3 = 0.f;
    float a4 = 0.f, a5 = 0.f, a6 = 0.f, a7 = 0.f;

    int j = beg;
    for (; j + 15 < end; j += 16) {
        int sa = eidx[j + g];
        int sb = eidx[j + 8 + g];
        uint4 ha = *(const uint4*)&h[(size_t)sa * C_OUT + c8];
        uint4 hb = *(const uint4*)&h[(size_t)sb * C_OUT + c8];
        a0 += bflo(ha.x); a1 += bfhi(ha.x); a2 += bflo(ha.y); a3 += bfhi(ha.y);
        a4 += bflo(ha.z); a5 += bfhi(ha.z); a6 += bflo(ha.w); a7 += bfhi(ha.w);
        a0 += bflo(hb.x); a1 += bfhi(hb.x); a2 += bflo(hb.y); a3 += bfhi(hb.y);
        a4 += bflo(hb.z); a5 += bfhi(hb.z); a6 += bflo(hb.w); a7 += bfhi(hb.w);
    }
    for (; j < end; j += 8) {
        int rem = end - j;
        int idx = j + ((g < rem) ? g : 0);
        int s = eidx[idx];
        float mq = (g < rem) ? 1.f : 0.f;
        uint4 hv = *(const uint4*)&h[(size_t)s * C_OUT + c8];
        a0 += bflo(hv.x) * mq; a1 += bfhi(hv.x) * mq;
        a2 += bflo(hv.y) * mq; a3 += bfhi(hv.y) * mq;
        a4 += bflo(hv.z) * mq; a5 += bfhi(hv.z) * mq;
        a6 += bflo(hv.w) * mq; a7 += bfhi(hv.w) * mq;
    }
#pragma unroll
    for (int off = 8; off < 64; off <<= 1) {
        a0 += __shfl_xor(a0, off, 64); a1 += __shfl_xor(a1, off, 64);
        a2 += __shfl_xor(a2, off, 64); a3 += __shfl_xor(a3, off, 64);
        a4 += __shfl_xor(a4, off, 64); a5 += __shfl_xor(a5, off, 64);
        a6 += __shfl_xor(a6, off, 64); a7 += __shfl_xor(a7, off, 64);
    }
    if (g == 0) {
        float di = dinv[node];
        uint4 sv = *(const uint4*)&h[(size_t)node * C_OUT + c8];
        float4 b0 = *(const float4*)&bias[c8];
        float4 b1 = *(const float4*)&bias[c8 + 4];
        float4 o0, o1;
        o0.x = (a0 + bflo(sv.x)) * di + b0.x;
        o0.y = (a1 + bfhi(sv.x)) * di + b0.y;
        o0.z = (a2 + bflo(sv.y)) * di + b0.z;
        o0.w = (a3 + bfhi(sv.y)) * di + b0.w;
        o1.x = (a4 + bflo(sv.z)) * di + b1.x;
        o1.y = (a5 + bfhi(sv.z)) * di + b1.y;
        o1.z = (a6 + bflo(sv.w)) * di + b1.z;
        o1.w = (a7 + bfhi(sv.w)) * di + b1.w;
        *(float4*)&out[(size_t)node * C_OUT + c8] = o0;
        *(float4*)&out[(size_t)node * C_OUT + c8 + 4] = o1;
    }
}

extern "C" void kernel_launch(void* const* d_in, const int* in_sizes, int n_in,
                              void* d_out, int out_size, void* d_ws, size_t ws_size,
                              hipStream_t stream) {
    const float* x = (const float*)d_in[0];
    const int* ei = (const int*)d_in[1];
    const float* W = (const float*)d_in[2];
    const float* bias = (const float*)d_in[3];
    float* out = (float*)d_out;

    const int n = in_sizes[0] / C_IN;  // 100000
    const int e = in_sizes[1] / 2;     // 3200000
    const int* src = ei;
    const int* dst = ei + e;

    const int nbin = (e + CHUNK - 1) / CHUNK;   // 782
    const int nbuck = (n + NPB - 1) / NPB;      // 782

    char* w = (char*)d_ws;
    unsigned short* h = (unsigned short*)w;  w += (size_t)n * C_OUT * 2;   // 12.8 MB
    int* sorted = (int*)w;                   w += (size_t)e * 4;           // 12.8 MB
    int* eidx = (int*)w;                     w += (size_t)e * 4;           // 12.8 MB
    float* dinv = (float*)w;                 w += (size_t)n * 4;
    int* rowptr = (int*)w;                   w += (size_t)(n + 1) * 4;
    int* table = (int*)w;                    w += (size_t)nbin * NB * 4;   // 3.2 MB
    int* tot = (int*)w;                      w += NB * 4;
    int* gbase = (int*)w;                    w += (NB + 1) * 4;
    unsigned short* WT = (unsigned short*)w; w += (size_t)C_OUT * C_IN * 2; // 32 KB

    k_wt<<<1, 256, 0, stream>>>(W, WT);
    k_hist2<<<nbin, 1024, 0, stream>>>(dst, table, e);
    kA2<<<NB, 256, 0, stream>>>(table, tot, nbin);
    kB<<<1, 1024, 0, stream>>>(tot, gbase, e);
    k_bin2<<<nbin, 1024, 0, stream>>>(src, dst, table, gbase, sorted, e);
    k_sort2<<<nbuck, 512, 0, stream>>>(sorted, gbase, eidx, rowptr, dinv, n, e);
    k_gemm<<<(n + 63) / 64, 256, 0, stream>>>(x, WT, dinv, h, n);
    k_gather<<<(n + 3) / 4, 256, 0, stream>>>(rowptr, eidx, h, dinv, bias, out, n);
}